// Round 4
// baseline (136.222 us; speedup 1.0000x reference)
//
#include <hip/hip_runtime.h>
#include <hip/hip_fp16.h>

constexpr int B_  = 8;
constexpr int LQ  = 8192;
constexpr int LK  = 1024;
constexpr int NF  = 64;
constexpr int PAD = 8;
constexpr int LDW = NF + PAD;     // 72 f16 = 144 B rows (LDS only)

typedef _Float16 f16x8 __attribute__((ext_vector_type(8)));
typedef float    f32x4 __attribute__((ext_vector_type(4)));

#define MFMA16(a, b, c) __builtin_amdgcn_mfma_f32_16x16x32_f16((a), (b), (c), 0, 0, 0)

__device__ __forceinline__ f16x8 cvt8(const float* p) {
  float4 a = ((const float4*)p)[0];
  float4 b = ((const float4*)p)[1];
  f16x8 r;
  r[0] = (_Float16)a.x; r[1] = (_Float16)a.y; r[2] = (_Float16)a.z; r[3] = (_Float16)a.w;
  r[4] = (_Float16)b.x; r[5] = (_Float16)b.y; r[6] = (_Float16)b.z; r[7] = (_Float16)b.w;
  return r;
}

__device__ __forceinline__ f16x8 ldf(const _Float16* p) { return *(const f16x8*)p; }

__device__ __forceinline__ void st_pk4(_Float16* dst, float a, float b, float c, float d) {
  auto lo = __builtin_amdgcn_cvt_pkrtz(a, b);
  auto hi = __builtin_amdgcn_cvt_pkrtz(c, d);
  auto v  = __builtin_shufflevector(lo, hi, 0, 1, 2, 3);
  *(decltype(v)*)dst = v;
}

// C-regs (u = blocks 2h+0, v = 2h+1) -> one A/B-frag half (8 f16), valid under
// the baked column permutation: position [h g g a r r] holds logical [h a g g r r].
__device__ __forceinline__ f16x8 pack8(f32x4 u, f32x4 v) {
  auto a  = __builtin_amdgcn_cvt_pkrtz(u[0], u[1]);
  auto b  = __builtin_amdgcn_cvt_pkrtz(u[2], u[3]);
  auto cc = __builtin_amdgcn_cvt_pkrtz(v[0], v[1]);
  auto d  = __builtin_amdgcn_cvt_pkrtz(v[2], v[3]);
  f16x8 r;
  r[0] = a[0];  r[1] = a[1];  r[2] = b[0]; r[3] = b[1];
  r[4] = cc[0]; r[5] = cc[1]; r[6] = d[0]; r[7] = d[1];
  return r;
}

// ---------------------------------------------------------------------------
// Kernel A (unchanged from R3): K = kv@Wk -> f16 [b][key][d-permuted];
// V = kv@Wv -> f16 [b][d][key-permuted]. grid = 128 x 256.
// ---------------------------------------------------------------------------
__global__ __launch_bounds__(256) void kv_proj_kernel(
    const float* __restrict__ kv, const float* __restrict__ Wk,
    const float* __restrict__ Wv, _Float16* __restrict__ Kb,
    _Float16* __restrict__ Vt) {
  __shared__ __align__(16) _Float16 wkT[NF][LDW];
  __shared__ __align__(16) _Float16 wvT[NF][LDW];
  __shared__ __align__(16) _Float16 ktile[64][LDW];
  __shared__ __align__(16) _Float16 vtileT[64][LDW];

  const int t    = threadIdx.x;
  const int wave = t >> 6, lane = t & 63, g = lane >> 4, c = lane & 15;
  const int b    = blockIdx.x >> 4;
  const int key_base = (blockIdx.x & 15) * 64;

#pragma unroll
  for (int i = 0; i < 16; ++i) {
    int idx = t + 256 * i;
    int e = idx >> 6, d = idx & 63;
    wkT[d][e] = (_Float16)Wk[idx];
    wvT[d][e] = (_Float16)Wv[idx];
  }

  const float* src = kv + ((size_t)b * LK + key_base + wave * 16 + c) * NF;
  f16x8 a0 = cvt8(src + g * 8);
  f16x8 a1 = cvt8(src + 32 + g * 8);
  __syncthreads();

#pragma unroll
  for (int mb = 0; mb < 4; ++mb) {
    f32x4 kacc = {0.f, 0.f, 0.f, 0.f};
    const _Float16* wk0 = &wkT[mb * 16 + c][g * 8];
    kacc = MFMA16(ldf(wk0),      a0, kacc);
    kacc = MFMA16(ldf(wk0 + 32), a1, kacc);
    st_pk4(&ktile[wave * 16 + c][(8 * (mb >> 1) + 2 * g + (mb & 1)) * 4],
           kacc[0], kacc[1], kacc[2], kacc[3]);

    f32x4 vacc = {0.f, 0.f, 0.f, 0.f};
    const _Float16* wv0 = &wvT[mb * 16 + c][g * 8];
    vacc = MFMA16(a0, ldf(wv0),      vacc);
    vacc = MFMA16(a1, ldf(wv0 + 32), vacc);
    st_pk4(&vtileT[mb * 16 + c][(8 * (wave >> 1) + 2 * g + (wave & 1)) * 4],
           vacc[0], vacc[1], vacc[2], vacc[3]);
  }
  __syncthreads();

  const int srow = t >> 2, scol = (t & 3) * 16;
  {
    float4* kd = (float4*)(Kb + ((size_t)b * LK + key_base + srow) * NF + scol);
    kd[0] = *(float4*)&ktile[srow][scol];
    kd[1] = *(float4*)&ktile[srow][scol + 8];
    float4* vd = (float4*)(Vt + ((size_t)b * NF + srow) * LK + key_base + scol);
    vd[0] = *(float4*)&vtileT[srow][scol];
    vd[1] = *(float4*)&vtileT[srow][scol + 8];
  }
}

// ---------------------------------------------------------------------------
// Kernel B: barrier-free flash attention. K/V fragments loaded DIRECTLY from
// global (L2-resident, perfectly coalesced, tile-invariant vaddrs); zero LDS
// traffic and zero __syncthreads in the K-loop. 4 waves x 32 q = 128 q/block,
// grid = 512 x 256. One barrier total (Wq^T staging).
// ---------------------------------------------------------------------------
__global__ __launch_bounds__(256) void attn_kernel(
    const float* __restrict__ x, const float* __restrict__ Wq,
    const _Float16* __restrict__ Kb, const _Float16* __restrict__ Vt,
    float* __restrict__ out) {
  __shared__ __align__(16) _Float16 wq[NF][LDW];   // Wq^T, log2e-folded

  const int t    = threadIdx.x;
  const int wave = t >> 6, lane = t & 63, g = lane >> 4, c = lane & 15;
  const int b    = blockIdx.x >> 6;          // 64 blocks per batch
  const int q_base = (blockIdx.x & 63) * 128;
  constexpr float LOG2E = 1.44269504088896f;

#pragma unroll
  for (int i = 0; i < 16; ++i) {
    int idx = t + 256 * i;
    wq[idx & 63][idx >> 6] = (_Float16)(Wq[idx] * LOG2E);
  }

  const _Float16* Kg = Kb + (size_t)b * LK * NF;
  const _Float16* Vg = Vt + (size_t)b * NF * LK;

  // Tile-0 fragments, issued before the barrier (in flight during staging)
  f16x8 kf[8], vf[8];
#pragma unroll
  for (int kb = 0; kb < 4; ++kb) {
    const _Float16* p = Kg + (kb * 16 + c) * NF + g * 8;
    kf[2 * kb] = ldf(p); kf[2 * kb + 1] = ldf(p + 32);
    const _Float16* q = Vg + (size_t)(kb * 16 + c) * LK + g * 8;
    vf[2 * kb] = ldf(q); vf[2 * kb + 1] = ldf(q + 32);
  }
  __syncthreads();  // wq ready

  // ---- Q^T = Wq^T · x^T; C-regs -> B-frags in-lane ----
  f16x8 qb[2][2];
#pragma unroll
  for (int s = 0; s < 2; ++s) {
    const float* xrow = x + ((size_t)b * LQ + q_base + wave * 32 + s * 16 + c) * NF;
    f16x8 xa0 = cvt8(xrow + g * 8);
    f16x8 xa1 = cvt8(xrow + 32 + g * 8);
    f32x4 qa[4];
#pragma unroll
    for (int mb = 0; mb < 4; ++mb) {
      qa[mb] = {0.f, 0.f, 0.f, 0.f};
      const _Float16* wq0 = &wq[mb * 16 + c][g * 8];
      qa[mb] = MFMA16(ldf(wq0),      xa0, qa[mb]);
      qa[mb] = MFMA16(ldf(wq0 + 32), xa1, qa[mb]);
    }
    qb[s][0] = pack8(qa[0], qa[1]);
    qb[s][1] = pack8(qa[2], qa[3]);
  }

  float m_s[2] = {-1e30f, -1e30f}, l_s[2] = {0.f, 0.f};
  f32x4 oacc[2][4];
#pragma unroll
  for (int s = 0; s < 2; ++s)
#pragma unroll
    for (int nb = 0; nb < 4; ++nb) oacc[s][nb] = {0.f, 0.f, 0.f, 0.f};

#pragma unroll 2
  for (int tile = 0; tile < 16; ++tile) {
    // ---- S^T = K·Q^T (consumes kf) ----
    f32x4 st[2][4];
#pragma unroll
    for (int kb = 0; kb < 4; ++kb) {
      st[0][kb] = {0.f, 0.f, 0.f, 0.f};
      st[1][kb] = {0.f, 0.f, 0.f, 0.f};
      st[0][kb] = MFMA16(kf[2 * kb], qb[0][0], st[0][kb]);
      st[0][kb] = MFMA16(kf[2 * kb + 1], qb[0][1], st[0][kb]);
      st[1][kb] = MFMA16(kf[2 * kb], qb[1][0], st[1][kb]);
      st[1][kb] = MFMA16(kf[2 * kb + 1], qb[1][1], st[1][kb]);
    }
    // prefetch next K tile (issue-to-use gap: softmax + PV)
    if (tile < 15) {
      const _Float16* kn = Kg + (size_t)(tile + 1) * 64 * NF;
#pragma unroll
      for (int kb = 0; kb < 4; ++kb) {
        const _Float16* p = kn + (kb * 16 + c) * NF + g * 8;
        kf[2 * kb] = ldf(p); kf[2 * kb + 1] = ldf(p + 32);
      }
    }

    // ---- online softmax (scalar state per lane; query = s*16+c) ----
    f16x8 pa[2][2];
#pragma unroll
    for (int s = 0; s < 2; ++s) {
      float tmax = st[s][0][0];
#pragma unroll
      for (int kb = 0; kb < 4; ++kb)
#pragma unroll
        for (int r = 0; r < 4; ++r) tmax = fmaxf(tmax, st[s][kb][r]);
      tmax = fmaxf(tmax, __shfl_xor(tmax, 16));
      tmax = fmaxf(tmax, __shfl_xor(tmax, 32));

      if (__ballot(tmax > m_s[s]) != 0) {
        float mnew  = fmaxf(m_s[s], tmax);
        float alpha = __builtin_amdgcn_exp2f(m_s[s] - mnew);
        m_s[s] = mnew;
        l_s[s] *= alpha;
        float aq[4];
#pragma unroll
        for (int r = 0; r < 4; ++r) aq[r] = __shfl(alpha, 4 * g + r);
#pragma unroll
        for (int nb = 0; nb < 4; ++nb)
#pragma unroll
          for (int r = 0; r < 4; ++r) oacc[s][nb][r] *= aq[r];
      }

      float rsum = 0.f;
#pragma unroll
      for (int kb = 0; kb < 4; ++kb)
#pragma unroll
        for (int r = 0; r < 4; ++r) {
          float p = __builtin_amdgcn_exp2f(st[s][kb][r] - m_s[s]);
          st[s][kb][r] = p;
          rsum += p;
        }
      rsum += __shfl_xor(rsum, 16);
      rsum += __shfl_xor(rsum, 32);
      l_s[s] += rsum;

      pa[s][0] = pack8(st[s][0], st[s][1]);
      pa[s][1] = pack8(st[s][2], st[s][3]);
    }

    // ---- O += P·V (consumes vf) ----
#pragma unroll
    for (int nb = 0; nb < 4; ++nb) {
      oacc[0][nb] = MFMA16(pa[0][0], vf[2 * nb],     oacc[0][nb]);
      oacc[0][nb] = MFMA16(pa[0][1], vf[2 * nb + 1], oacc[0][nb]);
      oacc[1][nb] = MFMA16(pa[1][0], vf[2 * nb],     oacc[1][nb]);
      oacc[1][nb] = MFMA16(pa[1][1], vf[2 * nb + 1], oacc[1][nb]);
    }
    // prefetch next V tile
    if (tile < 15) {
#pragma unroll
      for (int nb = 0; nb < 4; ++nb) {
        const _Float16* p = Vg + (size_t)(nb * 16 + c) * LK + (tile + 1) * 64 + g * 8;
        vf[2 * nb] = ldf(p); vf[2 * nb + 1] = ldf(p + 32);
      }
    }
  }

  // ---- epilogue ----
#pragma unroll
  for (int s = 0; s < 2; ++s) {
    float linv = 1.0f / l_s[s];
    float lq[4];
#pragma unroll
    for (int r = 0; r < 4; ++r) lq[r] = __shfl(linv, 4 * g + r);
#pragma unroll
    for (int nb = 0; nb < 4; ++nb)
#pragma unroll
      for (int r = 0; r < 4; ++r)
        out[((size_t)b * LQ + q_base + wave * 32 + s * 16 + 4 * g + r) * NF + nb * 16 + c] =
            oacc[s][nb][r] * lq[r];
  }
}

extern "C" void kernel_launch(void* const* d_in, const int* in_sizes, int n_in,
                              void* d_out, int out_size, void* d_ws, size_t ws_size,
                              hipStream_t stream) {
  const float* x  = (const float*)d_in[0];
  const float* kv = (const float*)d_in[1];
  const float* Wq = (const float*)d_in[2];
  const float* Wk = (const float*)d_in[3];
  const float* Wv = (const float*)d_in[4];
  float* out = (float*)d_out;

  _Float16* Kb = (_Float16*)d_ws;
  _Float16* Vt = Kb + (size_t)B_ * LK * NF;

  kv_proj_kernel<<<B_ * (LK / 64), 256, 0, stream>>>(kv, Wk, Wv, Kb, Vt);
  attn_kernel<<<B_ * (LQ / 128), 256, 0, stream>>>(x, Wq, Kb, Vt, out);
}

// Round 5
// 108.742 us; speedup vs baseline: 1.2527x; 1.2527x over previous
//
#include <hip/hip_runtime.h>
#include <hip/hip_fp16.h>

constexpr int B_  = 8;
constexpr int LQ  = 8192;
constexpr int LK  = 1024;
constexpr int NF  = 64;
constexpr int PAD = 8;
constexpr int LDW = NF + PAD;     // 72 f16 rows (padded LDS, used in proj + wq only)

typedef _Float16 f16x8 __attribute__((ext_vector_type(8)));
typedef float    f32x4 __attribute__((ext_vector_type(4)));

#define MFMA16(a, b, c) __builtin_amdgcn_mfma_f32_16x16x32_f16((a), (b), (c), 0, 0, 0)

__device__ __forceinline__ f16x8 cvt8(const float* p) {
  float4 a = ((const float4*)p)[0];
  float4 b = ((const float4*)p)[1];
  f16x8 r;
  r[0] = (_Float16)a.x; r[1] = (_Float16)a.y; r[2] = (_Float16)a.z; r[3] = (_Float16)a.w;
  r[4] = (_Float16)b.x; r[5] = (_Float16)b.y; r[6] = (_Float16)b.z; r[7] = (_Float16)b.w;
  return r;
}

__device__ __forceinline__ f16x8 ldf(const _Float16* p) { return *(const f16x8*)p; }

__device__ __forceinline__ void st_pk4(_Float16* dst, float a, float b, float c, float d) {
  auto lo = __builtin_amdgcn_cvt_pkrtz(a, b);
  auto hi = __builtin_amdgcn_cvt_pkrtz(c, d);
  auto v  = __builtin_shufflevector(lo, hi, 0, 1, 2, 3);
  *(decltype(v)*)dst = v;
}

// C-regs (u = blocks 2h+0, v = 2h+1) -> one A/B-frag half (8 f16), valid under
// the baked column permutation: position [h g g a r r] holds logical [h a g g r r].
__device__ __forceinline__ f16x8 pack8(f32x4 u, f32x4 v) {
  auto a  = __builtin_amdgcn_cvt_pkrtz(u[0], u[1]);
  auto b  = __builtin_amdgcn_cvt_pkrtz(u[2], u[3]);
  auto cc = __builtin_amdgcn_cvt_pkrtz(v[0], v[1]);
  auto d  = __builtin_amdgcn_cvt_pkrtz(v[2], v[3]);
  f16x8 r;
  r[0] = a[0];  r[1] = a[1];  r[2] = b[0]; r[3] = b[1];
  r[4] = cc[0]; r[5] = cc[1]; r[6] = d[0]; r[7] = d[1];
  return r;
}

// Async global->LDS DMA, 16 B/lane; LDS dst is wave-uniform base + lane*16.
__device__ __forceinline__ void dma16(const _Float16* g, _Float16* l) {
  __builtin_amdgcn_global_load_lds(
      (const __attribute__((address_space(1))) unsigned int*)g,
      (__attribute__((address_space(3))) unsigned int*)l, 16, 0, 0);
}

// ---------------------------------------------------------------------------
// Kernel A: K = kv@Wk, V = kv@Wv, written in FRAG-LINEAR tile layout:
//   per 64-key tile (4096 f16 each for K and V), f16 index
//     ((h*4 + kb)*64 + lane)*8 + j
//   K value: K[key = kb*16 + (lane&15)][dpos = 32h + 8*(lane>>4) + j]
//   V value: V^T[d  = kb*16 + (lane&15)][kpos = 32h + 8*(lane>>4) + j]
// (dpos/kpos are the baked permuted positions). grid = 128 x 256.
// ---------------------------------------------------------------------------
__global__ __launch_bounds__(256) void kv_proj_kernel(
    const float* __restrict__ kv, const float* __restrict__ Wk,
    const float* __restrict__ Wv, _Float16* __restrict__ Kb,
    _Float16* __restrict__ Vt) {
  __shared__ __align__(16) _Float16 wkT[NF][LDW];
  __shared__ __align__(16) _Float16 wvT[NF][LDW];
  __shared__ __align__(16) _Float16 ktile[64][LDW];   // [key-local][dpos]
  __shared__ __align__(16) _Float16 vtileT[64][LDW];  // [d][kpos-local]

  const int t    = threadIdx.x;
  const int wave = t >> 6, lane = t & 63, g = lane >> 4, c = lane & 15;
  const int b    = blockIdx.x >> 4;
  const int key_base = (blockIdx.x & 15) * 64;

#pragma unroll
  for (int i = 0; i < 16; ++i) {
    int idx = t + 256 * i;
    int e = idx >> 6, d = idx & 63;
    wkT[d][e] = (_Float16)Wk[idx];
    wvT[d][e] = (_Float16)Wv[idx];
  }

  const float* src = kv + ((size_t)b * LK + key_base + wave * 16 + c) * NF;
  f16x8 a0 = cvt8(src + g * 8);
  f16x8 a1 = cvt8(src + 32 + g * 8);
  __syncthreads();

#pragma unroll
  for (int mb = 0; mb < 4; ++mb) {
    // K^T: A = Wk^T, B = kv^T -> C rows = d, col = key = c
    f32x4 kacc = {0.f, 0.f, 0.f, 0.f};
    const _Float16* wk0 = &wkT[mb * 16 + c][g * 8];
    kacc = MFMA16(ldf(wk0),      a0, kacc);
    kacc = MFMA16(ldf(wk0 + 32), a1, kacc);
    st_pk4(&ktile[wave * 16 + c][(8 * (mb >> 1) + 2 * g + (mb & 1)) * 4],
           kacc[0], kacc[1], kacc[2], kacc[3]);

    // V: A = kv rows, B = Wv -> C rows = key, col = d
    f32x4 vacc = {0.f, 0.f, 0.f, 0.f};
    const _Float16* wv0 = &wvT[mb * 16 + c][g * 8];
    vacc = MFMA16(a0, ldf(wv0),      vacc);
    vacc = MFMA16(a1, ldf(wv0 + 32), vacc);
    st_pk4(&vtileT[mb * 16 + c][(8 * (wave >> 1) + 2 * g + (wave & 1)) * 4],
           vacc[0], vacc[1], vacc[2], vacc[3]);
  }
  __syncthreads();

  // Frag-linear tile stores, fully coalesced (16 B/thread x 2 reps, contiguous)
  _Float16* KbT = Kb + (size_t)blockIdx.x * 4096;   // blockIdx = b*16 + tile
  _Float16* VbT = Vt + (size_t)blockIdx.x * 4096;
#pragma unroll
  for (int rep = 0; rep < 2; ++rep) {
    int q  = t + rep * 256;          // chunk 0..511
    int li = q & 63;
    int gg = li >> 4, cc = li & 15;
    int kb = (q >> 6) & 3, h = q >> 8;
    *(f16x8*)(KbT + q * 8) = ldf(&ktile[kb * 16 + cc][32 * h + 8 * gg]);
    *(f16x8*)(VbT + q * 8) = ldf(&vtileT[kb * 16 + cc][32 * h + 8 * gg]);
  }
}

// ---------------------------------------------------------------------------
// Kernel B: fused Q-proj + flash attention. 4 waves x 32 q = 128 q/block,
// grid = 512 x 256. Double-buffered K/V tiles DMA'd via global_load_lds
// (frag-linear: staging = straight memcpy, frag reads = lane-sequential,
// conflict-free). One barrier per tile.
// ---------------------------------------------------------------------------
__global__ __launch_bounds__(256) void attn_kernel(
    const float* __restrict__ x, const float* __restrict__ Wq,
    const _Float16* __restrict__ Kb, const _Float16* __restrict__ Vt,
    float* __restrict__ out) {
  __shared__ __align__(16) _Float16 wq[NF][LDW];      // Wq^T, log2e-folded
  __shared__ __align__(16) _Float16 tiles[2][8192];   // [buf][0..4095 K | 4096..8191 V]

  const int t    = threadIdx.x;
  const int wave = t >> 6, lane = t & 63, g = lane >> 4, c = lane & 15;
  const int b    = blockIdx.x >> 6;
  const int q_base = (blockIdx.x & 63) * 128;
  constexpr float LOG2E = 1.44269504088896f;

  const _Float16* Kt = Kb + (size_t)b * 16 * 4096;
  const _Float16* Vg = Vt + (size_t)b * 16 * 4096;

#pragma unroll
  for (int i = 0; i < 16; ++i) {
    int idx = t + 256 * i;
    wq[idx & 63][idx >> 6] = (_Float16)(Wq[idx] * LOG2E);
  }

  // DMA tile 0 -> buf 0 (wave w stages chunks 4w..4w+3; 1 KB each)
#pragma unroll
  for (int q = 0; q < 4; ++q) {
    int ch = wave * 4 + q;
    const _Float16* src = (ch < 8 ? Kt + ch * 512 : Vg + ch * 512 - 4096) + lane * 8;
    dma16(src, &tiles[0][ch * 512]);
  }
  __syncthreads();  // wq + tile0 ready (barrier drains vmcnt)

  // ---- Q^T = Wq^T · x^T; C-regs -> B-frags in-lane ----
  f16x8 qb[2][2];
#pragma unroll
  for (int s = 0; s < 2; ++s) {
    const float* xrow = x + ((size_t)b * LQ + q_base + wave * 32 + s * 16 + c) * NF;
    f16x8 xa0 = cvt8(xrow + g * 8);
    f16x8 xa1 = cvt8(xrow + 32 + g * 8);
    f32x4 qa[4];
#pragma unroll
    for (int mb = 0; mb < 4; ++mb) {
      qa[mb] = {0.f, 0.f, 0.f, 0.f};
      const _Float16* wq0 = &wq[mb * 16 + c][g * 8];
      qa[mb] = MFMA16(ldf(wq0),      xa0, qa[mb]);
      qa[mb] = MFMA16(ldf(wq0 + 32), xa1, qa[mb]);
    }
    qb[s][0] = pack8(qa[0], qa[1]);
    qb[s][1] = pack8(qa[2], qa[3]);
  }

  float m_s[2] = {-1e30f, -1e30f}, l_s[2] = {0.f, 0.f};
  f32x4 oacc[2][4];
#pragma unroll
  for (int s = 0; s < 2; ++s)
#pragma unroll
    for (int nb = 0; nb < 4; ++nb) oacc[s][nb] = {0.f, 0.f, 0.f, 0.f};

#pragma unroll 2
  for (int tile = 0; tile < 16; ++tile) {
    const int buf = tile & 1;
    // DMA next tile into the other buffer (full compute phase in flight)
    if (tile < 15) {
      const _Float16* kn = Kt + (tile + 1) * 4096;
      const _Float16* vn = Vg + (tile + 1) * 4096;
#pragma unroll
      for (int q = 0; q < 4; ++q) {
        int ch = wave * 4 + q;
        const _Float16* src = (ch < 8 ? kn + ch * 512 : vn + ch * 512 - 4096) + lane * 8;
        dma16(src, &tiles[buf ^ 1][ch * 512]);
      }
    }
    const _Float16* tb = tiles[buf];

    // ---- S^T = K·Q^T (lane-sequential frag reads, conflict-free) ----
    f32x4 st[2][4];
#pragma unroll
    for (int kb = 0; kb < 4; ++kb) {
      f16x8 k0 = ldf(tb + (size_t)(kb * 64 + lane) * 8);
      f16x8 k1 = ldf(tb + (size_t)((kb + 4) * 64 + lane) * 8);
      st[0][kb] = {0.f, 0.f, 0.f, 0.f};
      st[1][kb] = {0.f, 0.f, 0.f, 0.f};
      st[0][kb] = MFMA16(k0, qb[0][0], st[0][kb]);
      st[0][kb] = MFMA16(k1, qb[0][1], st[0][kb]);
      st[1][kb] = MFMA16(k0, qb[1][0], st[1][kb]);
      st[1][kb] = MFMA16(k1, qb[1][1], st[1][kb]);
    }

    // ---- online softmax (scalar state; query = s*16 + c) ----
    f16x8 pa[2][2];
#pragma unroll
    for (int s = 0; s < 2; ++s) {
      float tmax = st[s][0][0];
#pragma unroll
      for (int kb = 0; kb < 4; ++kb)
#pragma unroll
        for (int r = 0; r < 4; ++r) tmax = fmaxf(tmax, st[s][kb][r]);
      tmax = fmaxf(tmax, __shfl_xor(tmax, 16));
      tmax = fmaxf(tmax, __shfl_xor(tmax, 32));

      if (__ballot(tmax > m_s[s]) != 0) {
        float mnew  = fmaxf(m_s[s], tmax);
        float alpha = __builtin_amdgcn_exp2f(m_s[s] - mnew);
        m_s[s] = mnew;
        l_s[s] *= alpha;
        float aq[4];
#pragma unroll
        for (int r = 0; r < 4; ++r) aq[r] = __shfl(alpha, 4 * g + r);
#pragma unroll
        for (int nb = 0; nb < 4; ++nb)
#pragma unroll
          for (int r = 0; r < 4; ++r) oacc[s][nb][r] *= aq[r];
      }

      float rsum = 0.f;
#pragma unroll
      for (int kb = 0; kb < 4; ++kb)
#pragma unroll
        for (int r = 0; r < 4; ++r) {
          float p = __builtin_amdgcn_exp2f(st[s][kb][r] - m_s[s]);
          st[s][kb][r] = p;
          rsum += p;
        }
      rsum += __shfl_xor(rsum, 16);
      rsum += __shfl_xor(rsum, 32);
      l_s[s] += rsum;

      pa[s][0] = pack8(st[s][0], st[s][1]);
      pa[s][1] = pack8(st[s][2], st[s][3]);
    }

    // ---- O += P·V ----
#pragma unroll
    for (int nb = 0; nb < 4; ++nb) {
      f16x8 v0 = ldf(tb + 4096 + (size_t)(nb * 64 + lane) * 8);
      f16x8 v1 = ldf(tb + 4096 + (size_t)((nb + 4) * 64 + lane) * 8);
      oacc[0][nb] = MFMA16(pa[0][0], v0, oacc[0][nb]);
      oacc[0][nb] = MFMA16(pa[0][1], v1, oacc[0][nb]);
      oacc[1][nb] = MFMA16(pa[1][0], v0, oacc[1][nb]);
      oacc[1][nb] = MFMA16(pa[1][1], v1, oacc[1][nb]);
    }
    __syncthreads();  // all waves done with buf; drains next-tile DMA
  }

  // ---- epilogue ----
#pragma unroll
  for (int s = 0; s < 2; ++s) {
    float linv = 1.0f / l_s[s];
    float lq[4];
#pragma unroll
    for (int r = 0; r < 4; ++r) lq[r] = __shfl(linv, 4 * g + r);
#pragma unroll
    for (int nb = 0; nb < 4; ++nb)
#pragma unroll
      for (int r = 0; r < 4; ++r)
        out[((size_t)b * LQ + q_base + wave * 32 + s * 16 + 4 * g + r) * NF + nb * 16 + c] =
            oacc[s][nb][r] * lq[r];
  }
}

extern "C" void kernel_launch(void* const* d_in, const int* in_sizes, int n_in,
                              void* d_out, int out_size, void* d_ws, size_t ws_size,
                              hipStream_t stream) {
  const float* x  = (const float*)d_in[0];
  const float* kv = (const float*)d_in[1];
  const float* Wq = (const float*)d_in[2];
  const float* Wk = (const float*)d_in[3];
  const float* Wv = (const float*)d_in[4];
  float* out = (float*)d_out;

  _Float16* Kb = (_Float16*)d_ws;
  _Float16* Vt = Kb + (size_t)B_ * LK * NF;

  kv_proj_kernel<<<B_ * (LK / 64), 256, 0, stream>>>(kv, Wk, Wv, Kb, Vt);
  attn_kernel<<<B_ * (LQ / 128), 256, 0, stream>>>(x, Wq, Kb, Vt, out);
}

// Round 6
// 104.183 us; speedup vs baseline: 1.3075x; 1.0438x over previous
//
#include <hip/hip_runtime.h>
#include <hip/hip_fp16.h>

constexpr int B_  = 8;
constexpr int LQ  = 8192;
constexpr int LK  = 1024;
constexpr int NF  = 64;
constexpr int PAD = 8;
constexpr int LDW = NF + PAD;     // 72 f16 rows (padded LDS in proj / wq staging)

typedef _Float16 f16x8 __attribute__((ext_vector_type(8)));
typedef float    f32x4 __attribute__((ext_vector_type(4)));

#define MFMA16(a, b, c) __builtin_amdgcn_mfma_f32_16x16x32_f16((a), (b), (c), 0, 0, 0)

__device__ __forceinline__ f16x8 cvt8(const float* p) {
  float4 a = ((const float4*)p)[0];
  float4 b = ((const float4*)p)[1];
  f16x8 r;
  r[0] = (_Float16)a.x; r[1] = (_Float16)a.y; r[2] = (_Float16)a.z; r[3] = (_Float16)a.w;
  r[4] = (_Float16)b.x; r[5] = (_Float16)b.y; r[6] = (_Float16)b.z; r[7] = (_Float16)b.w;
  return r;
}

__device__ __forceinline__ f16x8 ldf(const _Float16* p) { return *(const f16x8*)p; }

__device__ __forceinline__ void st_pk4(_Float16* dst, float a, float b, float c, float d) {
  auto lo = __builtin_amdgcn_cvt_pkrtz(a, b);
  auto hi = __builtin_amdgcn_cvt_pkrtz(c, d);
  auto v  = __builtin_shufflevector(lo, hi, 0, 1, 2, 3);
  *(decltype(v)*)dst = v;
}

// C-regs (u = 32-block even, v = odd) -> one A/B-frag half (8 f16), valid under
// the baked column permutation: position [h g g a r r] holds logical [h a g g r r].
__device__ __forceinline__ f16x8 pack8(f32x4 u, f32x4 v) {
  auto a  = __builtin_amdgcn_cvt_pkrtz(u[0], u[1]);
  auto b  = __builtin_amdgcn_cvt_pkrtz(u[2], u[3]);
  auto cc = __builtin_amdgcn_cvt_pkrtz(v[0], v[1]);
  auto d  = __builtin_amdgcn_cvt_pkrtz(v[2], v[3]);
  f16x8 r;
  r[0] = a[0];  r[1] = a[1];  r[2] = b[0]; r[3] = b[1];
  r[4] = cc[0]; r[5] = cc[1]; r[6] = d[0]; r[7] = d[1];
  return r;
}

// Async global->LDS DMA, 16 B/lane; LDS dst = wave-uniform base + lane*16.
__device__ __forceinline__ void dma16(const _Float16* g, _Float16* l) {
  __builtin_amdgcn_global_load_lds(
      (const __attribute__((address_space(1))) unsigned int*)g,
      (__attribute__((address_space(3))) unsigned int*)l, 16, 0, 0);
}

// Barrier WITHOUT the compiler's vmcnt-drain-after-prefetch: at call site the
// only outstanding vmem is the CURRENT tile's DMA (next tile not yet issued),
// so vmcnt(0) is cheap and the next DMA stays in flight across compute.
__device__ __forceinline__ void tile_barrier() {
  asm volatile("s_waitcnt vmcnt(0)\n\ts_barrier" ::: "memory");
}

// ---------------------------------------------------------------------------
// Kernel A: K = kv@Wk, V = kv@Wv, written frag-linear in 128-key tiles:
// per batch, tile T (0..7): [ K: 16 chunks | V: 16 chunks ], chunk = 64 lanes
// x 8 f16. K chunk h*8+kb holds K[key=kb*16+(lane&15)][dpos=32h+8*(lane>>4)+j];
// V chunk 16+(h'*4+nb) holds V^T[d=nb*16+(lane&15)][kpos=32h'+8*(lane>>4)+j].
// grid = B*(LK/64) = 128 x 256 (two proj blocks feed one 128-key tile).
// ---------------------------------------------------------------------------
__global__ __launch_bounds__(256) void kv_proj_kernel(
    const float* __restrict__ kv, const float* __restrict__ Wk,
    const float* __restrict__ Wv, _Float16* __restrict__ KV) {
  __shared__ __align__(16) _Float16 wkT[NF][LDW];
  __shared__ __align__(16) _Float16 wvT[NF][LDW];
  __shared__ __align__(16) _Float16 ktile[64][LDW];   // [key-local][dpos]
  __shared__ __align__(16) _Float16 vtileT[64][LDW];  // [d][kpos-local]

  const int t    = threadIdx.x;
  const int wave = t >> 6, lane = t & 63, g = lane >> 4, c = lane & 15;
  const int b    = blockIdx.x >> 4;
  const int t64  = blockIdx.x & 15;        // 64-key block index
  const int key_base = t64 * 64;

#pragma unroll
  for (int i = 0; i < 16; ++i) {
    int idx = t + 256 * i;
    int e = idx >> 6, d = idx & 63;
    wkT[d][e] = (_Float16)Wk[idx];
    wvT[d][e] = (_Float16)Wv[idx];
  }

  const float* src = kv + ((size_t)b * LK + key_base + wave * 16 + c) * NF;
  f16x8 a0 = cvt8(src + g * 8);
  f16x8 a1 = cvt8(src + 32 + g * 8);
  __syncthreads();

#pragma unroll
  for (int mb = 0; mb < 4; ++mb) {
    // K^T: A = Wk^T, B = kv^T -> C rows = d, col = key-local = c
    f32x4 kacc = {0.f, 0.f, 0.f, 0.f};
    const _Float16* wk0 = &wkT[mb * 16 + c][g * 8];
    kacc = MFMA16(ldf(wk0),      a0, kacc);
    kacc = MFMA16(ldf(wk0 + 32), a1, kacc);
    st_pk4(&ktile[wave * 16 + c][(8 * (mb >> 1) + 2 * g + (mb & 1)) * 4],
           kacc[0], kacc[1], kacc[2], kacc[3]);

    // V: A = kv rows, B = Wv -> C rows = key, col = d
    f32x4 vacc = {0.f, 0.f, 0.f, 0.f};
    const _Float16* wv0 = &wvT[mb * 16 + c][g * 8];
    vacc = MFMA16(a0, ldf(wv0),      vacc);
    vacc = MFMA16(a1, ldf(wv0 + 32), vacc);
    st_pk4(&vtileT[mb * 16 + c][(8 * (wave >> 1) + 2 * g + (wave & 1)) * 4],
           vacc[0], vacc[1], vacc[2], vacc[3]);
  }
  __syncthreads();

  // Frag-linear stores into the 128-key tile this 64-key block belongs to
  const int half = t64 & 1;
  _Float16* base = KV + ((size_t)b * 8 + (t64 >> 1)) * 16384;
#pragma unroll
  for (int rep = 0; rep < 2; ++rep) {
    int q   = t + rep * 256;               // 0..511
    int li  = q & 63;
    int gg  = li >> 4, cc = li & 15;
    int sub = (q >> 6) & 3, h = q >> 8;
    int ck  = h * 8 + half * 4 + sub;      // K chunk (kb = half*4+sub)
    int cv  = (half * 2 + h) * 4 + sub;    // V chunk (h' = half*2+h, nb = sub)
    *(f16x8*)(base + (ck * 64 + li) * 8)        = ldf(&ktile[sub * 16 + cc][32 * h + 8 * gg]);
    *(f16x8*)(base + 8192 + (cv * 64 + li) * 8) = ldf(&vtileT[sub * 16 + cc][32 * h + 8 * gg]);
  }
}

// ---------------------------------------------------------------------------
// Kernel B: fused Q-proj + flash attention. 4 waves x 32 q = 128 q/block,
// grid = 512 x 256. 128-key tiles (8 iters), truly-async double-buffered DMA
// (raw s_barrier, prefetch stays in flight), l accumulated by MFMA vs ones.
// LDS = 2 x 32 KB; Wq^T overlaid in buffer 1 (consumed before first overwrite).
// ---------------------------------------------------------------------------
__global__ __launch_bounds__(256) void attn_kernel(
    const float* __restrict__ x, const float* __restrict__ Wq,
    const _Float16* __restrict__ KV, float* __restrict__ out) {
  __shared__ __align__(16) _Float16 lds[2][16384];   // [buf][K 8192 | V 8192]

  const int t    = threadIdx.x;
  const int wave = t >> 6, lane = t & 63, g = lane >> 4, c = lane & 15;
  const int b    = blockIdx.x >> 6;
  const int q_base = (blockIdx.x & 63) * 128;
  constexpr float LOG2E = 1.44269504088896f;

  _Float16* wqp = &lds[1][0];              // Wq^T [64][LDW], log2e-folded
#pragma unroll
  for (int i = 0; i < 16; ++i) {
    int idx = t + 256 * i;
    wqp[(idx & 63) * LDW + (idx >> 6)] = (_Float16)(Wq[idx] * LOG2E);
  }

  const _Float16* Kt = KV + (size_t)b * 8 * 16384;
  // DMA tile 0 -> buf 0 (wave w: chunks 8w..8w+7, 1 KB each)
#pragma unroll
  for (int q = 0; q < 8; ++q) {
    int ch = wave * 8 + q;
    dma16(Kt + ch * 512 + lane * 8, &lds[0][ch * 512]);
  }
  __syncthreads();  // wq + tile0 ready

  // ---- Q^T = Wq^T · x^T; C-regs -> B-frags in-lane ----
  f16x8 qb[2][2];
#pragma unroll
  for (int s = 0; s < 2; ++s) {
    const float* xrow = x + ((size_t)b * LQ + q_base + wave * 32 + s * 16 + c) * NF;
    f16x8 xa0 = cvt8(xrow + g * 8);
    f16x8 xa1 = cvt8(xrow + 32 + g * 8);
    f32x4 qa[4];
#pragma unroll
    for (int mb = 0; mb < 4; ++mb) {
      qa[mb] = {0.f, 0.f, 0.f, 0.f};
      const _Float16* wq0 = &wqp[(mb * 16 + c) * LDW + g * 8];
      qa[mb] = MFMA16(ldf(wq0),      xa0, qa[mb]);
      qa[mb] = MFMA16(ldf(wq0 + 32), xa1, qa[mb]);
    }
    qb[s][0] = pack8(qa[0], qa[1]);
    qb[s][1] = pack8(qa[2], qa[3]);
  }

  f16x8 ones;
#pragma unroll
  for (int j = 0; j < 8; ++j) ones[j] = (_Float16)1.0f;

  float m_s[2] = {-1e30f, -1e30f};
  f32x4 lacc[2] = {{0.f, 0.f, 0.f, 0.f}, {0.f, 0.f, 0.f, 0.f}};
  f32x4 oacc[2][4];
#pragma unroll
  for (int s = 0; s < 2; ++s)
#pragma unroll
    for (int nb = 0; nb < 4; ++nb) oacc[s][nb] = {0.f, 0.f, 0.f, 0.f};

  for (int tile = 0; tile < 8; ++tile) {
    // Wait for THIS tile's DMA (only outstanding vmem), sync, then prefetch.
    tile_barrier();
    if (tile < 7) {
      const _Float16* nt = Kt + (size_t)(tile + 1) * 16384;
      _Float16* nb_ = &lds[(tile + 1) & 1][0];
#pragma unroll
      for (int q = 0; q < 8; ++q) {
        int ch = wave * 8 + q;
        dma16(nt + ch * 512 + lane * 8, nb_ + ch * 512);
      }
    }
    const _Float16* tb = &lds[tile & 1][0];

    // ---- S^T = K·Q^T over 128 keys (conflict-free lane-sequential reads) ----
    f32x4 st[2][8];
#pragma unroll
    for (int kb = 0; kb < 8; ++kb) {
      f16x8 k0 = ldf(tb + (size_t)(kb * 64 + lane) * 8);
      f16x8 k1 = ldf(tb + (size_t)((8 + kb) * 64 + lane) * 8);
      st[0][kb] = {0.f, 0.f, 0.f, 0.f};
      st[1][kb] = {0.f, 0.f, 0.f, 0.f};
      st[0][kb] = MFMA16(k0, qb[0][0], st[0][kb]);
      st[0][kb] = MFMA16(k1, qb[0][1], st[0][kb]);
      st[1][kb] = MFMA16(k0, qb[1][0], st[1][kb]);
      st[1][kb] = MFMA16(k1, qb[1][1], st[1][kb]);
    }

    // ---- online softmax (scalar m per lane; query = s*16 + c) ----
    f16x8 pa[2][4];
#pragma unroll
    for (int s = 0; s < 2; ++s) {
      float tmax = st[s][0][0];
#pragma unroll
      for (int kb = 0; kb < 8; ++kb)
#pragma unroll
        for (int r = 0; r < 4; ++r) tmax = fmaxf(tmax, st[s][kb][r]);
      tmax = fmaxf(tmax, __shfl_xor(tmax, 16));
      tmax = fmaxf(tmax, __shfl_xor(tmax, 32));

      if (__ballot(tmax > m_s[s]) != 0) {   // wave-uniform rescale gate
        float mnew  = fmaxf(m_s[s], tmax);
        float alpha = __builtin_amdgcn_exp2f(m_s[s] - mnew);
        m_s[s] = mnew;
        float aq[4];
#pragma unroll
        for (int r = 0; r < 4; ++r) aq[r] = __shfl(alpha, 4 * g + r);
#pragma unroll
        for (int r = 0; r < 4; ++r) lacc[s][r] *= aq[r];
#pragma unroll
        for (int nb = 0; nb < 4; ++nb)
#pragma unroll
          for (int r = 0; r < 4; ++r) oacc[s][nb][r] *= aq[r];
      }

#pragma unroll
      for (int kb = 0; kb < 8; ++kb)
#pragma unroll
        for (int r = 0; r < 4; ++r)
          st[s][kb][r] = __builtin_amdgcn_exp2f(st[s][kb][r] - m_s[s]);

      // C-regs -> A-frags in-lane (keys 32h'..32h'+31 per frag)
#pragma unroll
      for (int hh = 0; hh < 4; ++hh)
        pa[s][hh] = pack8(st[s][2 * hh], st[s][2 * hh + 1]);

      // l += P·1 via MFMA — lands in C-layout, exactly where epilogue needs it
#pragma unroll
      for (int hh = 0; hh < 4; ++hh)
        lacc[s] = MFMA16(pa[s][hh], ones, lacc[s]);
    }

    // ---- O += P·V ----
#pragma unroll
    for (int nb = 0; nb < 4; ++nb) {
#pragma unroll
      for (int hh = 0; hh < 4; ++hh) {
        f16x8 vf = ldf(tb + 8192 + (size_t)((hh * 4 + nb) * 64 + lane) * 8);
        oacc[0][nb] = MFMA16(pa[0][hh], vf, oacc[0][nb]);
        oacc[1][nb] = MFMA16(pa[1][hh], vf, oacc[1][nb]);
      }
    }
  }

  // ---- epilogue: O / l (l already in C-layout), fp32 store ----
#pragma unroll
  for (int s = 0; s < 2; ++s) {
    float linv[4];
#pragma unroll
    for (int r = 0; r < 4; ++r) linv[r] = 1.0f / lacc[s][r];
#pragma unroll
    for (int nb = 0; nb < 4; ++nb)
#pragma unroll
      for (int r = 0; r < 4; ++r)
        out[((size_t)b * LQ + q_base + wave * 32 + s * 16 + 4 * g + r) * NF + nb * 16 + c] =
            oacc[s][nb][r] * linv[r];
  }
}

extern "C" void kernel_launch(void* const* d_in, const int* in_sizes, int n_in,
                              void* d_out, int out_size, void* d_ws, size_t ws_size,
                              hipStream_t stream) {
  const float* x  = (const float*)d_in[0];
  const float* kv = (const float*)d_in[1];
  const float* Wq = (const float*)d_in[2];
  const float* Wk = (const float*)d_in[3];
  const float* Wv = (const float*)d_in[4];
  float* out = (float*)d_out;

  _Float16* KV = (_Float16*)d_ws;   // [B][8 tiles][K 8192 | V 8192] f16 = 2 MB

  kv_proj_kernel<<<B_ * (LK / 64), 256, 0, stream>>>(kv, Wk, Wv, KV);
  attn_kernel<<<B_ * (LQ / 128), 256, 0, stream>>>(x, Wq, KV, out);
}